// Round 5
// baseline (92.065 us; speedup 1.0000x reference)
//
#include <hip/hip_runtime.h>

typedef float f32x4 __attribute__((ext_vector_type(4)));

// out[e] = relu(relu(features[src[e]] @ W1 + b1) @ W2 + b2)
// Factored: per-node MLP (N=50k) into workspace, then per-edge gather (E=800k).

__device__ __forceinline__ float bcast(float v, int l) {
    return __int_as_float(__builtin_amdgcn_readlane(__float_as_int(v), l));
}

// One wave processes rows in a grid-stride loop. Lane j owns output column j:
// W1[:,j] and W2[:,j] live in 128 VGPRs (loaded once, reused for ~16 rows).
// x[k]/h[k] broadcasts via v_readlane (VALU) — no LDS, no per-FMA global loads.
__global__ __launch_bounds__(256, 3) void mlp_nodes_kernel(
    const float* __restrict__ features,
    const int* __restrict__ idx,   // nullptr: row -> features[row]; else features[idx[row]]
    const float* __restrict__ W1, const float* __restrict__ b1,
    const float* __restrict__ W2, const float* __restrict__ b2,
    float* __restrict__ out, int nrows)
{
    const int lane   = threadIdx.x & 63;
    const int wid    = (blockIdx.x * blockDim.x + threadIdx.x) >> 6;
    const int nwaves = (gridDim.x * blockDim.x) >> 6;

    float w1c[64], w2c[64];
    #pragma unroll
    for (int k = 0; k < 64; ++k) w1c[k] = W1[k * 64 + lane];
    #pragma unroll
    for (int k = 0; k < 64; ++k) w2c[k] = W2[k * 64 + lane];
    const float hb = b1[lane];
    const float yb = b2[lane];

    for (int row = wid; row < nrows; row += nwaves) {
        const int n = idx ? idx[row] : row;
        const float x = features[(long long)n * 64 + lane];

        // layer 1: h[lane] = relu(b1[lane] + sum_k x[k] * W1[k][lane])
        float a0 = hb, a1 = 0.f, a2 = 0.f, a3 = 0.f;
        #pragma unroll
        for (int k = 0; k < 64; k += 4) {
            a0 = fmaf(bcast(x, k + 0), w1c[k + 0], a0);
            a1 = fmaf(bcast(x, k + 1), w1c[k + 1], a1);
            a2 = fmaf(bcast(x, k + 2), w1c[k + 2], a2);
            a3 = fmaf(bcast(x, k + 3), w1c[k + 3], a3);
        }
        const float h = fmaxf((a0 + a1) + (a2 + a3), 0.0f);

        // layer 2: y[lane] = relu(b2[lane] + sum_k h[k] * W2[k][lane])
        float c0 = yb, c1 = 0.f, c2 = 0.f, c3 = 0.f;
        #pragma unroll
        for (int k = 0; k < 64; k += 4) {
            c0 = fmaf(bcast(h, k + 0), w2c[k + 0], c0);
            c1 = fmaf(bcast(h, k + 1), w2c[k + 1], c1);
            c2 = fmaf(bcast(h, k + 2), w2c[k + 2], c2);
            c3 = fmaf(bcast(h, k + 3), w2c[k + 3], c3);
        }
        out[(long long)row * 64 + lane] = fmaxf((c0 + c1) + (c2 + c3), 0.0f);
    }
}

// out[e][:] = Y[src[e]][:], 16 x float4 per edge.
// Regular (L2-allocating) stores — matches the ~7 TB/s fill-kernel path.
// Unrolled x4: all loads issued before any store -> 4 independent
// src->Y->store chains in flight per thread.
__global__ __launch_bounds__(256) void gather_kernel(
    const f32x4* __restrict__ Y,    // [N][16] float4
    const int* __restrict__ src,    // [E]
    f32x4* __restrict__ out,        // [E][16] float4
    long long total)                // E*16
{
    const long long stride = (long long)gridDim.x * blockDim.x;
    long long g = (long long)blockIdx.x * blockDim.x + threadIdx.x;

    for (; g + 3 * stride < total; g += 4 * stride) {
        const long long g0 = g, g1 = g + stride, g2 = g + 2 * stride, g3 = g + 3 * stride;
        const int n0 = src[g0 >> 4];
        const int n1 = src[g1 >> 4];
        const int n2 = src[g2 >> 4];
        const int n3 = src[g3 >> 4];
        const f32x4 v0 = Y[(long long)n0 * 16 + (g0 & 15)];
        const f32x4 v1 = Y[(long long)n1 * 16 + (g1 & 15)];
        const f32x4 v2 = Y[(long long)n2 * 16 + (g2 & 15)];
        const f32x4 v3 = Y[(long long)n3 * 16 + (g3 & 15)];
        out[g0] = v0;
        out[g1] = v1;
        out[g2] = v2;
        out[g3] = v3;
    }
    for (; g < total; g += stride) {
        const int n = src[g >> 4];
        out[g] = Y[(long long)n * 16 + (g & 15)];
    }
}

extern "C" void kernel_launch(void* const* d_in, const int* in_sizes, int n_in,
                              void* d_out, int out_size, void* d_ws, size_t ws_size,
                              hipStream_t stream) {
    const float* features = (const float*)d_in[0];
    const int*   src      = (const int*)  d_in[1];
    const float* W1       = (const float*)d_in[2];
    const float* b1       = (const float*)d_in[3];
    const float* W2       = (const float*)d_in[4];
    const float* b2       = (const float*)d_in[5];
    float* out = (float*)d_out;

    const int N = in_sizes[0] / 64;
    const int E = in_sizes[1];

    const size_t need = (size_t)N * 64 * sizeof(float);
    if (ws_size >= need) {
        // Phase 1: per-node MLP into workspace (3072 waves, ~16 rows/wave).
        float* Y = (float*)d_ws;
        mlp_nodes_kernel<<<768, 256, 0, stream>>>(
            features, nullptr, W1, b1, W2, b2, Y, N);
        // Phase 2: gather per edge (1M threads, 12.2 float4 each, unroll x4).
        const long long total = (long long)E * 16;
        gather_kernel<<<4096, 256, 0, stream>>>(
            (const f32x4*)Y, src, (f32x4*)out, total);
    } else {
        // Fallback: per-edge MLP directly into out (correct, slower)
        mlp_nodes_kernel<<<3072, 256, 0, stream>>>(
            features, src, W1, b1, W2, b2, out, E);
    }
}

// Round 6
// 76.417 us; speedup vs baseline: 1.2048x; 1.2048x over previous
//
#include <hip/hip_runtime.h>

typedef float f32x4 __attribute__((ext_vector_type(4)));
typedef _Float16 f16;
typedef f16 f16x8 __attribute__((ext_vector_type(8)));

// out[e] = relu(relu(features[src[e]] @ W1 + b1) @ W2 + b2)
// Phase 1: per-node MLP (N=50k) via f16 MFMA into ws; Phase 2: gather (E=800k).

// ---------------- Phase 1: MFMA MLP ----------------
// One wave computes a 16-row x 64-col output tile.
// A-frag  (16x32 f16): lane l holds x[r0+(l&15)][ (l>>4)*8 + j + 32*s ]
// B-frag  (32x16 f16): lane l holds W[ (l>>4)*8 + j + 32*s ][ 16*t + (l&15) ]
// D-frag  (16x16 f32): lane l holds y[ (l>>4)*4 + i ][ 16*t + (l&15) ]   (m89 mapping)
// Layer1 -> layer2 transpose goes through a wave-private LDS slice (no barriers).
__global__ __launch_bounds__(256) void mlp_mfma_kernel(
    const float* __restrict__ feat,
    const float* __restrict__ W1, const float* __restrict__ b1,
    const float* __restrict__ W2, const float* __restrict__ b2,
    float* __restrict__ Y, int N, int ntiles)
{
    __shared__ f16 hl[4][16][72];   // per-wave [16 rows][64 cols + pad]

    const int lane = threadIdx.x & 63;
    const int wv   = threadIdx.x >> 6;
    const int l15  = lane & 15;
    const int q    = lane >> 4;

    const int gw = blockIdx.x * 4 + wv;
    const int nw = gridDim.x * 4;

    // Weight fragments, held in registers for the whole kernel (64 VGPRs).
    f16x8 B1f[4][2], B2f[4][2];
    #pragma unroll
    for (int t = 0; t < 4; ++t) {
        #pragma unroll
        for (int s = 0; s < 2; ++s) {
            f16x8 r1, r2;
            #pragma unroll
            for (int j = 0; j < 8; ++j) {
                const int kk = s * 32 + q * 8 + j;
                r1[j] = (f16)W1[kk * 64 + t * 16 + l15];
                r2[j] = (f16)W2[kk * 64 + t * 16 + l15];
            }
            B1f[t][s] = r1;
            B2f[t][s] = r2;
        }
    }
    float bb1[4], bb2[4];
    #pragma unroll
    for (int t = 0; t < 4; ++t) {
        bb1[t] = b1[t * 16 + l15];
        bb2[t] = b2[t * 16 + l15];
    }

    for (int tile = gw; tile < ntiles; tile += nw) {
        const int r0 = tile * 16;
        const int rr = (r0 + l15 < N) ? (r0 + l15) : (N - 1);

        // A fragments from global (32B/lane, 16B-aligned), cvt to f16.
        f16x8 A[2];
        #pragma unroll
        for (int s = 0; s < 2; ++s) {
            const float* p = feat + (long long)rr * 64 + s * 32 + q * 8;
            f32x4 u0 = *(const f32x4*)p;
            f32x4 u1 = *(const f32x4*)(p + 4);
            f16x8 a;
            #pragma unroll
            for (int j = 0; j < 4; ++j) { a[j] = (f16)u0[j]; a[4 + j] = (f16)u1[j]; }
            A[s] = a;
        }

        // Layer 1: h = relu(x @ W1 + b1), acc init = bias (C[row][col]=b1[col]).
        f32x4 acc[4];
        #pragma unroll
        for (int t = 0; t < 4; ++t) acc[t] = (f32x4){bb1[t], bb1[t], bb1[t], bb1[t]};
        #pragma unroll
        for (int t = 0; t < 4; ++t) {
            acc[t] = __builtin_amdgcn_mfma_f32_16x16x32_f16(A[0], B1f[t][0], acc[t], 0, 0, 0);
            acc[t] = __builtin_amdgcn_mfma_f32_16x16x32_f16(A[1], B1f[t][1], acc[t], 0, 0, 0);
        }

        // relu + f16, write h to wave-private LDS in [row][col] layout.
        #pragma unroll
        for (int t = 0; t < 4; ++t)
            #pragma unroll
            for (int i = 0; i < 4; ++i)
                hl[wv][q * 4 + i][t * 16 + l15] = (f16)fmaxf(acc[t][i], 0.0f);

        // A2 fragments: lane reads h[l15][s*32+q*8 .. +7] (16B ds_read_b128).
        // Same-wave write->read dependency; compiler inserts lgkmcnt.
        f16x8 A2[2];
        #pragma unroll
        for (int s = 0; s < 2; ++s)
            A2[s] = *(const f16x8*)&hl[wv][l15][s * 32 + q * 8];

        // Layer 2: y = relu(h @ W2 + b2).
        f32x4 acc2[4];
        #pragma unroll
        for (int t = 0; t < 4; ++t) acc2[t] = (f32x4){bb2[t], bb2[t], bb2[t], bb2[t]};
        #pragma unroll
        for (int t = 0; t < 4; ++t) {
            acc2[t] = __builtin_amdgcn_mfma_f32_16x16x32_f16(A2[0], B2f[t][0], acc2[t], 0, 0, 0);
            acc2[t] = __builtin_amdgcn_mfma_f32_16x16x32_f16(A2[1], B2f[t][1], acc2[t], 0, 0, 0);
        }

        // Store: per (t,i) lanes 0-15 write 64B contiguous.
        #pragma unroll
        for (int t = 0; t < 4; ++t)
            #pragma unroll
            for (int i = 0; i < 4; ++i) {
                const int row = r0 + q * 4 + i;
                if (row < N)
                    Y[(long long)row * 64 + t * 16 + l15] = fmaxf(acc2[t][i], 0.0f);
            }
    }
}

// ---------------- Fallback MLP (ws too small): readlane broadcast ----------------
__device__ __forceinline__ float bcast(float v, int l) {
    return __int_as_float(__builtin_amdgcn_readlane(__float_as_int(v), l));
}

__global__ __launch_bounds__(256, 3) void mlp_nodes_kernel(
    const float* __restrict__ features,
    const int* __restrict__ idx,
    const float* __restrict__ W1, const float* __restrict__ b1,
    const float* __restrict__ W2, const float* __restrict__ b2,
    float* __restrict__ out, int nrows)
{
    const int lane   = threadIdx.x & 63;
    const int wid    = (blockIdx.x * blockDim.x + threadIdx.x) >> 6;
    const int nwaves = (gridDim.x * blockDim.x) >> 6;

    float w1c[64], w2c[64];
    #pragma unroll
    for (int k = 0; k < 64; ++k) w1c[k] = W1[k * 64 + lane];
    #pragma unroll
    for (int k = 0; k < 64; ++k) w2c[k] = W2[k * 64 + lane];
    const float hb = b1[lane];
    const float yb = b2[lane];

    for (int row = wid; row < nrows; row += nwaves) {
        const int n = idx ? idx[row] : row;
        const float x = features[(long long)n * 64 + lane];
        float a0 = hb, a1 = 0.f, a2 = 0.f, a3 = 0.f;
        #pragma unroll
        for (int k = 0; k < 64; k += 4) {
            a0 = fmaf(bcast(x, k + 0), w1c[k + 0], a0);
            a1 = fmaf(bcast(x, k + 1), w1c[k + 1], a1);
            a2 = fmaf(bcast(x, k + 2), w1c[k + 2], a2);
            a3 = fmaf(bcast(x, k + 3), w1c[k + 3], a3);
        }
        const float h = fmaxf((a0 + a1) + (a2 + a3), 0.0f);
        float c0 = yb, c1 = 0.f, c2 = 0.f, c3 = 0.f;
        #pragma unroll
        for (int k = 0; k < 64; k += 4) {
            c0 = fmaf(bcast(h, k + 0), w2c[k + 0], c0);
            c1 = fmaf(bcast(h, k + 1), w2c[k + 1], c1);
            c2 = fmaf(bcast(h, k + 2), w2c[k + 2], c2);
            c3 = fmaf(bcast(h, k + 3), w2c[k + 3], c3);
        }
        out[(long long)row * 64 + lane] = fmaxf((c0 + c1) + (c2 + c3), 0.0f);
    }
}

// ---------------- Phase 2: gather ----------------
__global__ __launch_bounds__(256) void gather_kernel(
    const f32x4* __restrict__ Y,    // [N][16] float4
    const int* __restrict__ src,    // [E]
    f32x4* __restrict__ out,        // [E][16] float4
    long long total)                // E*16
{
    const long long stride = (long long)gridDim.x * blockDim.x;
    long long g = (long long)blockIdx.x * blockDim.x + threadIdx.x;

    for (; g + 3 * stride < total; g += 4 * stride) {
        const long long g0 = g, g1 = g + stride, g2 = g + 2 * stride, g3 = g + 3 * stride;
        const int n0 = src[g0 >> 4];
        const int n1 = src[g1 >> 4];
        const int n2 = src[g2 >> 4];
        const int n3 = src[g3 >> 4];
        const f32x4 v0 = Y[(long long)n0 * 16 + (g0 & 15)];
        const f32x4 v1 = Y[(long long)n1 * 16 + (g1 & 15)];
        const f32x4 v2 = Y[(long long)n2 * 16 + (g2 & 15)];
        const f32x4 v3 = Y[(long long)n3 * 16 + (g3 & 15)];
        out[g0] = v0;
        out[g1] = v1;
        out[g2] = v2;
        out[g3] = v3;
    }
    for (; g < total; g += stride) {
        const int n = src[g >> 4];
        out[g] = Y[(long long)n * 16 + (g & 15)];
    }
}

extern "C" void kernel_launch(void* const* d_in, const int* in_sizes, int n_in,
                              void* d_out, int out_size, void* d_ws, size_t ws_size,
                              hipStream_t stream) {
    const float* features = (const float*)d_in[0];
    const int*   src      = (const int*)  d_in[1];
    const float* W1       = (const float*)d_in[2];
    const float* b1       = (const float*)d_in[3];
    const float* W2       = (const float*)d_in[4];
    const float* b2       = (const float*)d_in[5];
    float* out = (float*)d_out;

    const int N = in_sizes[0] / 64;
    const int E = in_sizes[1];

    const size_t need = (size_t)N * 64 * sizeof(float);
    if (ws_size >= need) {
        float* Y = (float*)d_ws;
        const int ntiles = (N + 15) / 16;
        // 256 blocks x 4 waves = 1024 waves; ~3 tiles/wave amortizes the
        // 128-load weight-fragment prologue.
        mlp_mfma_kernel<<<256, 256, 0, stream>>>(
            features, W1, b1, W2, b2, Y, N, ntiles);
        const long long total = (long long)E * 16;
        gather_kernel<<<4096, 256, 0, stream>>>(
            (const f32x4*)Y, src, (f32x4*)out, total);
    } else {
        mlp_nodes_kernel<<<3072, 256, 0, stream>>>(
            features, src, W1, b1, W2, b2, out, E);
    }
}

// Round 7
// 67.175 us; speedup vs baseline: 1.3705x; 1.1376x over previous
//
#include <hip/hip_runtime.h>

typedef float f32x4 __attribute__((ext_vector_type(4)));
typedef _Float16 f16;
typedef f16 f16x8 __attribute__((ext_vector_type(8)));

// out[e] = relu(relu(features[src[e]] @ W1 + b1) @ W2 + b2)
// Fused: tiny cvt kernel (features f32 -> f16 in ws), then one kernel that
// gathers f16 feature rows per edge and runs the 2-layer MLP via f16 MFMA
// directly into out. Read-request volume halves vs f32; no Y round-trip.

// ---------------- features f32 -> f16 ----------------
__global__ __launch_bounds__(256) void cvt_kernel(
    const f32x4* __restrict__ in, f16x8* __restrict__ outv, int n8)
{
    const int stride = gridDim.x * blockDim.x;
    for (int i = blockIdx.x * blockDim.x + threadIdx.x; i < n8; i += stride) {
        const f32x4 a = in[2 * i];
        const f32x4 b = in[2 * i + 1];
        f16x8 o;
        #pragma unroll
        for (int j = 0; j < 4; ++j) { o[j] = (f16)a[j]; o[4 + j] = (f16)b[j]; }
        outv[i] = o;
    }
}

// ---------------- fused gather + MFMA MLP ----------------
// One wave computes a 16-edge x 64-col output tile.
// A-frag  (16x32 f16): lane l holds x[e0+(l&15)][ (l>>4)*8 + j + 32*s ]
//   gathered: row n = src[e0 + (l&15)], 16B f16x8 load per s.
// B-frag  (32x16 f16): lane l holds W[ (l>>4)*8 + j + 32*s ][ 16*t + (l&15) ]
// D-frag  (16x16 f32): lane l holds y[ (l>>4)*4 + i ][ 16*t + (l&15) ]
// Layer1 -> layer2 transpose via wave-private LDS slice (no barriers).
__global__ __launch_bounds__(256) void fused_mlp_kernel(
    const f16* __restrict__ feat16,  // [N][64]
    const int* __restrict__ src,     // [E]
    const float* __restrict__ W1, const float* __restrict__ b1,
    const float* __restrict__ W2, const float* __restrict__ b2,
    float* __restrict__ out, int E, int ntiles)
{
    __shared__ f16 hl[4][16][72];    // per-wave [16 rows][64 cols + pad]

    const int lane = threadIdx.x & 63;
    const int wv   = threadIdx.x >> 6;
    const int l15  = lane & 15;
    const int q    = lane >> 4;

    const int gw = blockIdx.x * 4 + wv;
    const int nw = gridDim.x * 4;

    // Weight fragments in registers for the whole kernel (64 VGPRs).
    f16x8 B1f[4][2], B2f[4][2];
    #pragma unroll
    for (int t = 0; t < 4; ++t) {
        #pragma unroll
        for (int s = 0; s < 2; ++s) {
            f16x8 r1, r2;
            #pragma unroll
            for (int j = 0; j < 8; ++j) {
                const int kk = s * 32 + q * 8 + j;
                r1[j] = (f16)W1[kk * 64 + t * 16 + l15];
                r2[j] = (f16)W2[kk * 64 + t * 16 + l15];
            }
            B1f[t][s] = r1;
            B2f[t][s] = r2;
        }
    }
    float bb1[4], bb2[4];
    #pragma unroll
    for (int t = 0; t < 4; ++t) {
        bb1[t] = b1[t * 16 + l15];
        bb2[t] = b2[t * 16 + l15];
    }

    for (int tile = gw; tile < ntiles; tile += nw) {
        const int e0 = tile * 16;
        int er = e0 + l15;
        if (er >= E) er = E - 1;
        const int n = src[er];

        // Gather A fragments: 2 x 16B f16x8 loads from the edge's source row.
        const f16* fp = feat16 + (long long)n * 64;
        const f16x8 A0 = *(const f16x8*)(fp + q * 8);
        const f16x8 A1 = *(const f16x8*)(fp + 32 + q * 8);

        // Layer 1: h = relu(x @ W1 + b1).
        f32x4 acc[4];
        #pragma unroll
        for (int t = 0; t < 4; ++t) acc[t] = (f32x4){bb1[t], bb1[t], bb1[t], bb1[t]};
        #pragma unroll
        for (int t = 0; t < 4; ++t) {
            acc[t] = __builtin_amdgcn_mfma_f32_16x16x32_f16(A0, B1f[t][0], acc[t], 0, 0, 0);
            acc[t] = __builtin_amdgcn_mfma_f32_16x16x32_f16(A1, B1f[t][1], acc[t], 0, 0, 0);
        }

        // relu + f16, stage h in wave-private LDS [row][col].
        #pragma unroll
        for (int t = 0; t < 4; ++t)
            #pragma unroll
            for (int i = 0; i < 4; ++i)
                hl[wv][q * 4 + i][t * 16 + l15] = (f16)fmaxf(acc[t][i], 0.0f);

        // A2: lane reads h[l15][s*32+q*8..+7] (16B ds_read_b128, same wave).
        const f16x8 A2a = *(const f16x8*)&hl[wv][l15][q * 8];
        const f16x8 A2b = *(const f16x8*)&hl[wv][l15][32 + q * 8];

        // Layer 2: y = relu(h @ W2 + b2).
        f32x4 acc2[4];
        #pragma unroll
        for (int t = 0; t < 4; ++t) acc2[t] = (f32x4){bb2[t], bb2[t], bb2[t], bb2[t]};
        #pragma unroll
        for (int t = 0; t < 4; ++t) {
            acc2[t] = __builtin_amdgcn_mfma_f32_16x16x32_f16(A2a, B2f[t][0], acc2[t], 0, 0, 0);
            acc2[t] = __builtin_amdgcn_mfma_f32_16x16x32_f16(A2b, B2f[t][1], acc2[t], 0, 0, 0);
        }

        // Store: per (t,i) lanes 0-15 write 64B contiguous into out.
        #pragma unroll
        for (int t = 0; t < 4; ++t)
            #pragma unroll
            for (int i = 0; i < 4; ++i) {
                const int row = e0 + q * 4 + i;
                if (row < E)
                    out[(long long)row * 64 + t * 16 + l15] = fmaxf(acc2[t][i], 0.0f);
            }
    }
}

// ---------------- Fallback (ws too small): per-edge readlane MLP ----------------
__device__ __forceinline__ float bcast(float v, int l) {
    return __int_as_float(__builtin_amdgcn_readlane(__float_as_int(v), l));
}

__global__ __launch_bounds__(256, 3) void mlp_nodes_kernel(
    const float* __restrict__ features,
    const int* __restrict__ idx,
    const float* __restrict__ W1, const float* __restrict__ b1,
    const float* __restrict__ W2, const float* __restrict__ b2,
    float* __restrict__ out, int nrows)
{
    const int lane   = threadIdx.x & 63;
    const int wid    = (blockIdx.x * blockDim.x + threadIdx.x) >> 6;
    const int nwaves = (gridDim.x * blockDim.x) >> 6;

    float w1c[64], w2c[64];
    #pragma unroll
    for (int k = 0; k < 64; ++k) w1c[k] = W1[k * 64 + lane];
    #pragma unroll
    for (int k = 0; k < 64; ++k) w2c[k] = W2[k * 64 + lane];
    const float hb = b1[lane];
    const float yb = b2[lane];

    for (int row = wid; row < nrows; row += nwaves) {
        const int n = idx ? idx[row] : row;
        const float x = features[(long long)n * 64 + lane];
        float a0 = hb, a1 = 0.f, a2 = 0.f, a3 = 0.f;
        #pragma unroll
        for (int k = 0; k < 64; k += 4) {
            a0 = fmaf(bcast(x, k + 0), w1c[k + 0], a0);
            a1 = fmaf(bcast(x, k + 1), w1c[k + 1], a1);
            a2 = fmaf(bcast(x, k + 2), w1c[k + 2], a2);
            a3 = fmaf(bcast(x, k + 3), w1c[k + 3], a3);
        }
        const float h = fmaxf((a0 + a1) + (a2 + a3), 0.0f);
        float c0 = yb, c1 = 0.f, c2 = 0.f, c3 = 0.f;
        #pragma unroll
        for (int k = 0; k < 64; k += 4) {
            c0 = fmaf(bcast(h, k + 0), w2c[k + 0], c0);
            c1 = fmaf(bcast(h, k + 1), w2c[k + 1], c1);
            c2 = fmaf(bcast(h, k + 2), w2c[k + 2], c2);
            c3 = fmaf(bcast(h, k + 3), w2c[k + 3], c3);
        }
        out[(long long)row * 64 + lane] = fmaxf((c0 + c1) + (c2 + c3), 0.0f);
    }
}

extern "C" void kernel_launch(void* const* d_in, const int* in_sizes, int n_in,
                              void* d_out, int out_size, void* d_ws, size_t ws_size,
                              hipStream_t stream) {
    const float* features = (const float*)d_in[0];
    const int*   src      = (const int*)  d_in[1];
    const float* W1       = (const float*)d_in[2];
    const float* b1       = (const float*)d_in[3];
    const float* W2       = (const float*)d_in[4];
    const float* b2       = (const float*)d_in[5];
    float* out = (float*)d_out;

    const int N = in_sizes[0] / 64;
    const int E = in_sizes[1];

    const size_t need = (size_t)N * 64 * sizeof(f16);
    if (ws_size >= need) {
        f16* feat16 = (f16*)d_ws;
        // features f32 -> f16 (12.8 MB read, 6.4 MB write; ~3 us).
        cvt_kernel<<<1024, 256, 0, stream>>>(
            (const f32x4*)features, (f16x8*)feat16, N * 8);
        // Fused per-edge MFMA MLP: 50k tiles over 4096 waves (~12 tiles/wave
        // amortizes the 128-load weight prologue; 16 waves/CU resident).
        const int ntiles = (E + 15) / 16;
        fused_mlp_kernel<<<1024, 256, 0, stream>>>(
            feat16, src, W1, b1, W2, b2, out, E, ntiles);
    } else {
        mlp_nodes_kernel<<<3072, 256, 0, stream>>>(
            features, src, W1, b1, W2, b2, out, E);
    }
}

// Round 8
// 66.098 us; speedup vs baseline: 1.3929x; 1.0163x over previous
//
#include <hip/hip_runtime.h>

typedef float f32x4 __attribute__((ext_vector_type(4)));
typedef _Float16 f16;
typedef f16 f16x8 __attribute__((ext_vector_type(8)));

// out[e] = relu(relu(features[src[e]] @ W1 + b1) @ W2 + b2)
// cvt kernel: features f32 -> f16 in ws. fused kernel: per-edge gather + 2-layer
// MFMA MLP directly into out, with LDS-transposed fully-coalesced stores
// (1 KB contiguous per wave-instruction) and next-tile gather prefetch.

// ---------------- features f32 -> f16 ----------------
__global__ __launch_bounds__(256) void cvt_kernel(
    const f32x4* __restrict__ in, f16x8* __restrict__ outv, int n8)
{
    const int stride = gridDim.x * blockDim.x;
    for (int i = blockIdx.x * blockDim.x + threadIdx.x; i < n8; i += stride) {
        const f32x4 a = in[2 * i];
        const f32x4 b = in[2 * i + 1];
        f16x8 o;
        #pragma unroll
        for (int j = 0; j < 4; ++j) { o[j] = (f16)a[j]; o[4 + j] = (f16)b[j]; }
        outv[i] = o;
    }
}

// ---------------- fused gather + MFMA MLP ----------------
// One wave computes a 16-edge x 64-col output tile.
// A-frag  (16x32 f16): lane l holds x[e0+(l&15)][ (l>>4)*8 + j + 32*s ]
// B-frag  (32x16 f16): lane l holds W[ (l>>4)*8 + j + 32*s ][ 16*t + (l&15) ]
// D-frag  (16x16 f32): lane l holds y[ (l>>4)*4 + i ][ 16*t + (l&15) ]
// h transpose via wave-private LDS (f16); output tile transposed via
// wave-private LDS (f32, ld=68 -> 16B-aligned reads, 2-way-free writes),
// then 4 stores x 1KB contiguous (lane byte addr = 16*lane).
__global__ __launch_bounds__(256) void fused_mlp_kernel(
    const f16* __restrict__ feat16,  // [N][64]
    const int* __restrict__ src,     // [E]
    const float* __restrict__ W1, const float* __restrict__ b1,
    const float* __restrict__ W2, const float* __restrict__ b2,
    float* __restrict__ out, int E, int ntiles)
{
    __shared__ f16  hl[4][16][72];   // h staging, per wave
    __shared__ float ol[4][16][68];  // out-tile staging, per wave

    const int lane = threadIdx.x & 63;
    const int wv   = threadIdx.x >> 6;
    const int l15  = lane & 15;
    const int q    = lane >> 4;

    const int gw = blockIdx.x * 4 + wv;
    const int nw = gridDim.x * 4;

    // Weight fragments in registers for the whole kernel.
    f16x8 B1f[4][2], B2f[4][2];
    #pragma unroll
    for (int t = 0; t < 4; ++t) {
        #pragma unroll
        for (int s = 0; s < 2; ++s) {
            f16x8 r1, r2;
            #pragma unroll
            for (int j = 0; j < 8; ++j) {
                const int kk = s * 32 + q * 8 + j;
                r1[j] = (f16)W1[kk * 64 + t * 16 + l15];
                r2[j] = (f16)W2[kk * 64 + t * 16 + l15];
            }
            B1f[t][s] = r1;
            B2f[t][s] = r2;
        }
    }
    float bb1[4], bb2[4];
    #pragma unroll
    for (int t = 0; t < 4; ++t) {
        bb1[t] = b1[t * 16 + l15];
        bb2[t] = b2[t * 16 + l15];
    }

    int tile = gw;
    if (tile >= ntiles) return;

    // Preload tile 0's gather (src + A fragments).
    {
        int er = tile * 16 + l15;
        if (er >= E) er = E - 1;
        // fallthrough into loop below with A0/A1 live
    }
    int er0 = tile * 16 + l15; if (er0 >= E) er0 = E - 1;
    int n = src[er0];
    const f16* fp0 = feat16 + (long long)n * 64;
    f16x8 A0 = *(const f16x8*)(fp0 + q * 8);
    f16x8 A1 = *(const f16x8*)(fp0 + 32 + q * 8);

    while (tile < ntiles) {
        const int e0 = tile * 16;
        const int tile_n = tile + nw;

        // Prefetch next tile's gather; latency hides under this tile's MFMAs.
        f16x8 nA0, nA1;
        if (tile_n < ntiles) {
            int er = tile_n * 16 + l15;
            if (er >= E) er = E - 1;
            const int nn = src[er];
            const f16* fp = feat16 + (long long)nn * 64;
            nA0 = *(const f16x8*)(fp + q * 8);
            nA1 = *(const f16x8*)(fp + 32 + q * 8);
        }

        // Layer 1: h = relu(x @ W1 + b1).
        f32x4 acc[4];
        #pragma unroll
        for (int t = 0; t < 4; ++t) acc[t] = (f32x4){bb1[t], bb1[t], bb1[t], bb1[t]};
        #pragma unroll
        for (int t = 0; t < 4; ++t) {
            acc[t] = __builtin_amdgcn_mfma_f32_16x16x32_f16(A0, B1f[t][0], acc[t], 0, 0, 0);
            acc[t] = __builtin_amdgcn_mfma_f32_16x16x32_f16(A1, B1f[t][1], acc[t], 0, 0, 0);
        }

        // relu + f16, stage h in wave-private LDS [row][col].
        #pragma unroll
        for (int t = 0; t < 4; ++t)
            #pragma unroll
            for (int i = 0; i < 4; ++i)
                hl[wv][q * 4 + i][t * 16 + l15] = (f16)fmaxf(acc[t][i], 0.0f);

        // A2: lane reads h[l15][s*32+q*8..+7] (16B ds_read_b128, same wave).
        const f16x8 A2a = *(const f16x8*)&hl[wv][l15][q * 8];
        const f16x8 A2b = *(const f16x8*)&hl[wv][l15][32 + q * 8];

        // Layer 2: y = relu(h @ W2 + b2).
        f32x4 acc2[4];
        #pragma unroll
        for (int t = 0; t < 4; ++t) acc2[t] = (f32x4){bb2[t], bb2[t], bb2[t], bb2[t]};
        #pragma unroll
        for (int t = 0; t < 4; ++t) {
            acc2[t] = __builtin_amdgcn_mfma_f32_16x16x32_f16(A2a, B2f[t][0], acc2[t], 0, 0, 0);
            acc2[t] = __builtin_amdgcn_mfma_f32_16x16x32_f16(A2b, B2f[t][1], acc2[t], 0, 0, 0);
        }

        if (e0 + 16 <= E) {
            // Stage relu(y) in LDS [row][col] (banks: 2-way on writes = free).
            #pragma unroll
            for (int t = 0; t < 4; ++t)
                #pragma unroll
                for (int i = 0; i < 4; ++i)
                    ol[wv][q * 4 + i][t * 16 + l15] = fmaxf(acc2[t][i], 0.0f);
            // 4 stores, each exactly 1KB contiguous: lane byte offset = 16*lane.
            #pragma unroll
            for (int j = 0; j < 4; ++j) {
                const f32x4 v = *(const f32x4*)&ol[wv][4 * j + q][l15 * 4];
                *(f32x4*)&out[(long long)(e0 + 4 * j + q) * 64 + l15 * 4] = v;
            }
        } else {
            // Tail tile: guarded scattered stores.
            #pragma unroll
            for (int t = 0; t < 4; ++t)
                #pragma unroll
                for (int i = 0; i < 4; ++i) {
                    const int row = e0 + q * 4 + i;
                    if (row < E)
                        out[(long long)row * 64 + t * 16 + l15] = fmaxf(acc2[t][i], 0.0f);
                }
        }

        A0 = nA0;
        A1 = nA1;
        tile = tile_n;
    }
}

// ---------------- Fallback (ws too small): per-edge readlane MLP ----------------
__device__ __forceinline__ float bcast(float v, int l) {
    return __int_as_float(__builtin_amdgcn_readlane(__float_as_int(v), l));
}

__global__ __launch_bounds__(256, 3) void mlp_nodes_kernel(
    const float* __restrict__ features,
    const int* __restrict__ idx,
    const float* __restrict__ W1, const float* __restrict__ b1,
    const float* __restrict__ W2, const float* __restrict__ b2,
    float* __restrict__ out, int nrows)
{
    const int lane   = threadIdx.x & 63;
    const int wid    = (blockIdx.x * blockDim.x + threadIdx.x) >> 6;
    const int nwaves = (gridDim.x * blockDim.x) >> 6;

    float w1c[64], w2c[64];
    #pragma unroll
    for (int k = 0; k < 64; ++k) w1c[k] = W1[k * 64 + lane];
    #pragma unroll
    for (int k = 0; k < 64; ++k) w2c[k] = W2[k * 64 + lane];
    const float hb = b1[lane];
    const float yb = b2[lane];

    for (int row = wid; row < nrows; row += nwaves) {
        const int n = idx ? idx[row] : row;
        const float x = features[(long long)n * 64 + lane];
        float a0 = hb, a1 = 0.f, a2 = 0.f, a3 = 0.f;
        #pragma unroll
        for (int k = 0; k < 64; k += 4) {
            a0 = fmaf(bcast(x, k + 0), w1c[k + 0], a0);
            a1 = fmaf(bcast(x, k + 1), w1c[k + 1], a1);
            a2 = fmaf(bcast(x, k + 2), w1c[k + 2], a2);
            a3 = fmaf(bcast(x, k + 3), w1c[k + 3], a3);
        }
        const float h = fmaxf((a0 + a1) + (a2 + a3), 0.0f);
        float c0 = yb, c1 = 0.f, c2 = 0.f, c3 = 0.f;
        #pragma unroll
        for (int k = 0; k < 64; k += 4) {
            c0 = fmaf(bcast(h, k + 0), w2c[k + 0], c0);
            c1 = fmaf(bcast(h, k + 1), w2c[k + 1], c1);
            c2 = fmaf(bcast(h, k + 2), w2c[k + 2], c2);
            c3 = fmaf(bcast(h, k + 3), w2c[k + 3], c3);
        }
        out[(long long)row * 64 + lane] = fmaxf((c0 + c1) + (c2 + c3), 0.0f);
    }
}

extern "C" void kernel_launch(void* const* d_in, const int* in_sizes, int n_in,
                              void* d_out, int out_size, void* d_ws, size_t ws_size,
                              hipStream_t stream) {
    const float* features = (const float*)d_in[0];
    const int*   src      = (const int*)  d_in[1];
    const float* W1       = (const float*)d_in[2];
    const float* b1       = (const float*)d_in[3];
    const float* W2       = (const float*)d_in[4];
    const float* b2       = (const float*)d_in[5];
    float* out = (float*)d_out;

    const int N = in_sizes[0] / 64;
    const int E = in_sizes[1];

    const size_t need = (size_t)N * 64 * sizeof(f16);
    if (ws_size >= need) {
        f16* feat16 = (f16*)d_ws;
        cvt_kernel<<<1024, 256, 0, stream>>>(
            (const f32x4*)features, (f16x8*)feat16, N * 8);
        const int ntiles = (E + 15) / 16;
        // 1024 blocks x 4 waves = 4096 waves, ~12 tiles/wave.
        fused_mlp_kernel<<<1024, 256, 0, stream>>>(
            feat16, src, W1, b1, W2, b2, out, E, ntiles);
    } else {
        mlp_nodes_kernel<<<3072, 256, 0, stream>>>(
            features, src, W1, b1, W2, b2, out, E);
    }
}